// Round 1
// baseline (76.818 us; speedup 1.0000x reference)
//
#include <hip/hip_runtime.h>

// RBF-MMD discriminator: B=512 rows, T=128 slabs, C=16, fp32.
// out = E_xx - 2*E_xy over per-slab RBF grams (slab weight 1 for t in {0,127},
// else 2; 254 weighted slab instances).
//
// R9 structure: R8's per-entry math (pure-bf16 dot, norm channels folded into
// MFMA K-slots 16/17, log2-domain row scale) is kept verbatim — R8 proved
// per-entry cost is no longer the bottleneck (halving it moved 71.8->70.9us).
// The remaining cost is block-convoy overhead: 3328 tiny blocks each exposing
// an uncoalesced 64B/lane global load behind a barrier before ~1us of math.
// Fix (T14 async-STAGE): grid (26,32), each block owns 4 consecutive t-slabs.
//  - unit u+1's global loads issue BEFORE unit u's MFMA/exp compute; the
//    vmcnt wait lands in the post-compute LDS stage -> latency hidden.
//  - LDS double-buffered, ONE barrier per unit (was 2 per block).
//  - cross-wave red[] reduce dropped: each wave's lane0 writes part[idx*4+w].
// Kxx symmetry: strip-pairs q>=a only, q>a weighted 2x (exact).

#define LOG2E 1.4426950408889634f
#define SCALE 1.2011224087864498f   // sqrt(LOG2E)

typedef __attribute__((ext_vector_type(8))) __bf16 bf16x8;
typedef __attribute__((ext_vector_type(4))) float floatx4;

union FragU { uint4 q; unsigned int u[4]; bf16x8 v; };

// 16B-aligned group-padded LDS row offset (dwords): 8 dw/row + 4 dw pad per 4 rows.
static __device__ __forceinline__ int off(int n) { return (n << 3) + ((n >> 2) << 2); }

static __device__ __forceinline__ unsigned short bfbits(__bf16 h) {
    union { __bf16 h; unsigned short s; } u; u.h = h; return u.s;
}
static __device__ __forceinline__ unsigned int packhh(__bf16 a, __bf16 b) {
    return (unsigned int)bfbits(a) | ((unsigned int)bfbits(b) << 16);
}

#define NSLOT 26
#define ONEONE 0x3F803F80u   // packed bf16 {1.0, 1.0}

// grid (26,32): blockIdx.x = pair slot, blockIdx.y -> t0 = 4*by, units t0..t0+3.
// slot<16: xy block, a=slot>>2 (A strip of X), q=slot&3 (col strip of Y).
// slot>=16: xx block over triangular (a,q), q>=a, weight 2 if q>a.
// 4 waves; wave w owns A rows a*128 + w*32 (two 16-row tiles).
__global__ __launch_bounds__(256, 4) void mmd_kernel(const float* __restrict__ x,
                                                     const float* __restrict__ y,
                                                     float* __restrict__ part) {
    __shared__ unsigned int AH[2][1152], BH[2][1152];
    __shared__ unsigned int BG[2][512];   // per B-row: {pack(-ghi,-glo),0,0,0}
    __shared__ float srg[2][128];         // g per A-row
    __shared__ unsigned int zero4[4];

    const int slot = blockIdx.x;
    const int t0   = blockIdx.y << 2;
    const int tid  = threadIdx.x;
    const int w    = tid >> 6;
    const int lane = tid & 63;
    const int quad = lane >> 4;
    const int l15  = lane & 15;
    const int qh   = quad & 1;

    int sa, sq, isxx;
    if (slot < 16) { isxx = 0; sa = slot >> 2; sq = slot & 3; }
    else {
        isxx = 1;
        const int s = slot - 16;
        if      (s < 4) { sa = 0; sq = s; }
        else if (s < 7) { sa = 1; sq = s - 3; }
        else if (s < 9) { sa = 2; sq = s - 5; }
        else            { sa = 3; sq = 3; }
    }

    if (tid == 0) { zero4[0] = 0u; zero4[1] = 0u; zero4[2] = 0u; zero4[3] = 0u; }

    // ---- staging constants: threads 0..127 handle A-rows (X), 128..255 B-rows ----
    const int half = tid >> 7;
    const int r    = tid & 127;
    const int grow = (half ? sq : sa) * 128 + r;
    const float4* __restrict__ src4 =
        (half && !isxx) ? (const float4*)y : (const float4*)x;
    const size_t gb = (size_t)grow * 512 + (size_t)t0 * 4;   // float4 units

    // prefetch registers (one unit = 64B/thread, 4 contiguous float4)
    float4 pf0 = src4[gb], pf1 = src4[gb + 1], pf2 = src4[gb + 2], pf3 = src4[gb + 3];

    // convert prefetch regs -> LDS buffer b (bf16 pack + log2-domain norms)
    auto stage = [&](int b) {
        const float fs[16] = { pf0.x, pf0.y, pf0.z, pf0.w, pf1.x, pf1.y, pf1.z, pf1.w,
                               pf2.x, pf2.y, pf2.z, pf2.w, pf3.x, pf3.y, pf3.z, pf3.w };
        float g = 0.f;
        unsigned int hw[8];
#pragma unroll
        for (int p = 0; p < 8; ++p) {
            const float v0 = fs[2 * p], v1 = fs[2 * p + 1];
            g += v0 * v0 + v1 * v1;
            hw[p] = packhh((__bf16)(v0 * SCALE), (__bf16)(v1 * SCALE));
        }
        const float gp = 0.5f * LOG2E * g;   // log2-domain column/row norm
        unsigned int* __restrict__ H = half ? &BH[b][0] : &AH[b][0];
        const int o = off(r);
        *(uint4*)&H[o]     = make_uint4(hw[0], hw[1], hw[2], hw[3]);
        *(uint4*)&H[o + 4] = make_uint4(hw[4], hw[5], hw[6], hw[7]);
        if (half) {
            // -g as hi+lo bf16 (residual ~6e-5 in the exponent)
            const __bf16 nh = (__bf16)(-gp);
            const __bf16 nl = (__bf16)(-(gp + (float)nh));
            *(uint4*)&BG[b][r * 4] = make_uint4(packhh(nh, nl), 0u, 0u, 0u);
        } else {
            srg[b][r] = gp;
        }
    };

    stage(0);
    __syncthreads();

#pragma unroll
    for (int u = 0; u < 4; ++u) {
        const int b = u & 1;

        // issue next unit's global loads NOW; the vmcnt wait lands in stage()
        // after this unit's compute -> HBM/L2 latency hidden under MFMA+exp.
        if (u < 3) {
            const size_t gu = gb + (size_t)(u + 1) * 4;
            pf0 = src4[gu]; pf1 = src4[gu + 1]; pf2 = src4[gu + 2]; pf3 = src4[gu + 3];
        }

        // ---- A fragments: quads 0/1 = data (k0..15); quad 2 = {1,1,0..}
        //      (k16,k17 multiply B's -g channels); quad 3 = zeros ----
        bf16x8 a1f[2];
#pragma unroll
        for (int rt = 0; rt < 2; ++rt) {
            FragU fu;
            if (quad < 2) {
                const int row = w * 32 + rt * 16 + l15;
                fu.q = *(const uint4*)&AH[b][off(row) + qh * 4];
            } else {
                fu.q = make_uint4((quad == 2) ? ONEONE : 0u, 0u, 0u, 0u);
            }
            a1f[rt] = fu.v;
        }

        // per-lane B-fragment base pointer + per-jt stride (dwords)
        const unsigned int* bptr;
        int bstride;
        if (quad < 2)       { bptr = &BH[b][off(l15) + qh * 4]; bstride = 144; }
        else if (quad == 2) { bptr = &BG[b][l15 * 4];           bstride = 64;  }
        else                { bptr = &zero4[0];                 bstride = 0;   }

        float sum[2][4] = {{0.f, 0.f, 0.f, 0.f}, {0.f, 0.f, 0.f, 0.f}};

        // ---- software-pipelined tile loop: MFMA tile jt, exp tile jt-1 ----
        floatx4 accP[2], accC[2];
        {
            FragU bf; bf.q = *(const uint4*)bptr; bptr += bstride;
            floatx4 zc = {0.f, 0.f, 0.f, 0.f};
            accP[0] = __builtin_amdgcn_mfma_f32_16x16x32_bf16(a1f[0], bf.v, zc, 0, 0, 0);
            accP[1] = __builtin_amdgcn_mfma_f32_16x16x32_bf16(a1f[1], bf.v, zc, 0, 0, 0);
        }
#pragma unroll
        for (int jt = 1; jt < 8; ++jt) {
            FragU bf; bf.q = *(const uint4*)bptr; bptr += bstride;
            floatx4 zc = {0.f, 0.f, 0.f, 0.f};
            accC[0] = __builtin_amdgcn_mfma_f32_16x16x32_bf16(a1f[0], bf.v, zc, 0, 0, 0);
            accC[1] = __builtin_amdgcn_mfma_f32_16x16x32_bf16(a1f[1], bf.v, zc, 0, 0, 0);
#pragma unroll
            for (int rt = 0; rt < 2; ++rt)
#pragma unroll
                for (int rr = 0; rr < 4; ++rr)
                    sum[rt][rr] += __builtin_amdgcn_exp2f(accP[rt][rr]);
            accP[0] = accC[0];
            accP[1] = accC[1];
        }
#pragma unroll
        for (int rt = 0; rt < 2; ++rt)
#pragma unroll
            for (int rr = 0; rr < 4; ++rr)
                sum[rt][rr] += __builtin_amdgcn_exp2f(accP[rt][rr]);

        // ---- epilogue: row-scale by 2^-g_row, wave reduce, per-wave store ----
        float tot = 0.f;
#pragma unroll
        for (int rt = 0; rt < 2; ++rt)
#pragma unroll
            for (int rr = 0; rr < 4; ++rr) {
                const float rs =
                    __builtin_amdgcn_exp2f(-srg[b][w * 32 + rt * 16 + quad * 4 + rr]);
                tot = fmaf(sum[rt][rr], rs, tot);
            }
        for (int o2 = 32; o2 > 0; o2 >>= 1) tot += __shfl_down(tot, o2, 64);

        if (lane == 0) {
            const int t = t0 + u;
            float wt = (t == 0 || t == 127) ? 1.f : 2.f;
            if (isxx && sq > sa) wt *= 2.f;   // symmetric off-diag strip-pair
            const int idx = isxx ? (2048 + t * 10 + (slot - 16)) : (t * 16 + slot);
            part[idx * 4 + w] = wt * tot;     // per-wave partial, no block reduce
        }

        // ---- write-late: convert prefetched regs into the other buffer ----
        if (u < 3) {
            stage(b ^ 1);
            __syncthreads();
        }
    }
}

__global__ __launch_bounds__(256) void finalize_kernel(const float* __restrict__ part,
                                                       float* __restrict__ out) {
    const int tid = threadIdx.x;
    double vxy = 0.0, vxx = 0.0;
#pragma unroll
    for (int k = 0; k < 32; ++k)  vxy += (double)part[tid + 256 * k];   // [0,8192)
#pragma unroll
    for (int k = 32; k < 52; ++k) vxx += (double)part[tid + 256 * k];   // [8192,13312)
    for (int o = 32; o > 0; o >>= 1) {
        vxx += __shfl_down(vxx, o, 64);
        vxy += __shfl_down(vxy, o, 64);
    }
    __shared__ double red[8];
    const int wid = tid >> 6;
    if ((tid & 63) == 0) { red[wid] = vxx; red[4 + wid] = vxy; }
    __syncthreads();
    if (tid == 0) {
        double sxx = red[0] + red[1] + red[2] + red[3];
        double sxy = red[4] + red[5] + red[6] + red[7];
        // diagonal entries (~1.0 each) included in sxx: subtract 254*512
        double e1 = (sxx - 254.0 * 512.0) / (254.0 * 512.0 * 511.0);
        double e2 = sxy / (254.0 * 512.0 * 512.0);
        out[0] = (float)(e1 - 2.0 * e2);
    }
}

extern "C" void kernel_launch(void* const* d_in, const int* in_sizes, int n_in,
                              void* d_out, int out_size, void* d_ws, size_t ws_size,
                              hipStream_t stream) {
    (void)in_sizes; (void)n_in; (void)out_size; (void)ws_size;
    const float* x = (const float*)d_in[0];
    const float* y = (const float*)d_in[1];
    float* out  = (float*)d_out;
    float* part = (float*)d_ws;   // 13312 floats: [0,8192) xy, [8192,13312) xx

    mmd_kernel<<<dim3(NSLOT, 32), dim3(256), 0, stream>>>(x, y, part);
    finalize_kernel<<<dim3(1), dim3(256), 0, stream>>>(part, out);
}

// Round 2
// 71.310 us; speedup vs baseline: 1.0772x; 1.0772x over previous
//
#include <hip/hip_runtime.h>

// RBF-MMD discriminator: B=512 rows, T=128 slabs, C=16, fp32.
// out = E_xx - 2*E_xy over per-slab RBF grams (slab weight 1 for t in {0,127},
// else 2; 254 weighted slab instances).
//
// R10 structure: R8's shape restored (grid (26,128), 1 t-slab per block,
// 11.9KB LDS, high residency ~8 blocks/CU) after R9's 4-unit batching
// regressed (+6us: 832 blocks -> 3.25/CU, 33% granularity tail, exposed
// stage latency). Single change vs R8: the cross-wave red[] reduce +
// second __syncthreads is dropped — each wave's lane0 stores its own
// weighted partial to part[idx*4+w]; finalize sums 13312 floats.
// Per-entry math unchanged from R8: pure-bf16 dot (SCALE=sqrt(log2e) folded
// into operands), -|col|^2/2 in log2 domain folded into MFMA K-slots 16/17
// via hi+lo bf16 channels against A={1,1}, row-scale 2^-g_row epilogue.
// Kxx symmetry: strip-pairs q>=a only, q>a weighted 2x (exact).

#define LOG2E 1.4426950408889634f
#define SCALE 1.2011224087864498f   // sqrt(LOG2E)

typedef __attribute__((ext_vector_type(8))) __bf16 bf16x8;
typedef __attribute__((ext_vector_type(4))) float floatx4;

union FragU { uint4 q; unsigned int u[4]; bf16x8 v; };

// 16B-aligned group-padded LDS row offset (dwords): 8 dw/row + 4 dw pad per 4 rows.
static __device__ __forceinline__ int off(int n) { return (n << 3) + ((n >> 2) << 2); }

static __device__ __forceinline__ unsigned short bfbits(__bf16 h) {
    union { __bf16 h; unsigned short s; } u; u.h = h; return u.s;
}
static __device__ __forceinline__ unsigned int packhh(__bf16 a, __bf16 b) {
    return (unsigned int)bfbits(a) | ((unsigned int)bfbits(b) << 16);
}

#define NSLOT 26
#define ONEONE 0x3F803F80u   // packed bf16 {1.0, 1.0}

// grid (26,128): blockIdx.x = pair slot, blockIdx.y = t.
// slot<16: xy block, a=slot>>2 (A strip of X), q=slot&3 (col strip of Y).
// slot>=16: xx block over triangular (a,q), q>=a, weight 2 if q>a.
// 4 waves; wave w owns A rows a*128 + w*32 (two 16-row tiles).
__global__ __launch_bounds__(256, 8) void mmd_kernel(const float* __restrict__ x,
                                                     const float* __restrict__ y,
                                                     float* __restrict__ part) {
    __shared__ unsigned int AH[1152], BH[1152];
    __shared__ unsigned int BG[512];      // per B-row: {pack(-ghi,-glo),0,0,0}
    __shared__ float srg[128];            // g per A-row
    __shared__ unsigned int zero4[4];

    const int slot = blockIdx.x;
    const int t    = blockIdx.y;
    const int tid  = threadIdx.x;
    const int w    = tid >> 6;
    const int lane = tid & 63;
    const int quad = lane >> 4;
    const int l15  = lane & 15;
    const int qh   = quad & 1;

    int sa, sq, isxx;
    if (slot < 16) { isxx = 0; sa = slot >> 2; sq = slot & 3; }
    else {
        isxx = 1;
        const int s = slot - 16;
        if      (s < 4) { sa = 0; sq = s; }
        else if (s < 7) { sa = 1; sq = s - 3; }
        else if (s < 9) { sa = 2; sq = s - 5; }
        else            { sa = 3; sq = 3; }
    }

    if (tid == 0) { zero4[0] = 0u; zero4[1] = 0u; zero4[2] = 0u; zero4[3] = 0u; }

    // ---- staging: threads 0..127 convert A-rows (X), 128..255 B-rows ----
    {
        const int half = tid >> 7;
        const int r    = tid & 127;
        const int grow = (half ? sq : sa) * 128 + r;
        const float4* __restrict__ src4 =
            (half && !isxx) ? (const float4*)y : (const float4*)x;
        const size_t gb = (size_t)grow * 512 + t * 4;
        float4 f0 = src4[gb], f1 = src4[gb + 1], f2 = src4[gb + 2], f3 = src4[gb + 3];
        const float fs[16] = { f0.x, f0.y, f0.z, f0.w, f1.x, f1.y, f1.z, f1.w,
                               f2.x, f2.y, f2.z, f2.w, f3.x, f3.y, f3.z, f3.w };
        float g = 0.f;
        unsigned int hw[8];
#pragma unroll
        for (int p = 0; p < 8; ++p) {
            const float v0 = fs[2 * p], v1 = fs[2 * p + 1];
            g += v0 * v0 + v1 * v1;
            hw[p] = packhh((__bf16)(v0 * SCALE), (__bf16)(v1 * SCALE));
        }
        const float gp = 0.5f * LOG2E * g;   // log2-domain column/row norm
        unsigned int* __restrict__ H = half ? BH : AH;
        const int o = off(r);
        *(uint4*)&H[o]     = make_uint4(hw[0], hw[1], hw[2], hw[3]);
        *(uint4*)&H[o + 4] = make_uint4(hw[4], hw[5], hw[6], hw[7]);
        if (half) {
            // -g as hi+lo bf16 (residual ~6e-5 in the exponent)
            const __bf16 nh = (__bf16)(-gp);
            const __bf16 nl = (__bf16)(-(gp + (float)nh));
            *(uint4*)&BG[r * 4] = make_uint4(packhh(nh, nl), 0u, 0u, 0u);
        } else {
            srg[r] = gp;
        }
    }
    __syncthreads();

    // ---- A fragments: quads 0/1 = hi data (k0..15); quad 2 = {1,1,0..}
    //      (k16,k17 multiply B's -g channels); quad 3 = zeros ----
    bf16x8 a1f[2];
    {
#pragma unroll
        for (int rt = 0; rt < 2; ++rt) {
            FragU u;
            if (quad < 2) {
                const int row = w * 32 + rt * 16 + l15;
                u.q = *(const uint4*)&AH[off(row) + qh * 4];
            } else {
                u.q = make_uint4((quad == 2) ? ONEONE : 0u, 0u, 0u, 0u);
            }
            a1f[rt] = u.v;
        }
    }

    // per-lane B-fragment base pointer + per-jt stride (dwords)
    const unsigned int* bptr;
    int bstride;
    if (quad < 2)      { bptr = &BH[off(l15) + qh * 4]; bstride = 144; }
    else if (quad == 2){ bptr = &BG[l15 * 4];           bstride = 64;  }
    else               { bptr = &zero4[0];              bstride = 0;   }

    float sum[2][4] = {{0.f, 0.f, 0.f, 0.f}, {0.f, 0.f, 0.f, 0.f}};

    // ---- software-pipelined main loop: MFMA tile jt, exp tile jt-1 ----
    floatx4 accP[2], accC[2];
    {
        FragU b; b.q = *(const uint4*)bptr; bptr += bstride;
        floatx4 zc = {0.f, 0.f, 0.f, 0.f};
        accP[0] = __builtin_amdgcn_mfma_f32_16x16x32_bf16(a1f[0], b.v, zc, 0, 0, 0);
        accP[1] = __builtin_amdgcn_mfma_f32_16x16x32_bf16(a1f[1], b.v, zc, 0, 0, 0);
    }
#pragma unroll
    for (int jt = 1; jt < 8; ++jt) {
        FragU b; b.q = *(const uint4*)bptr; bptr += bstride;
        floatx4 zc = {0.f, 0.f, 0.f, 0.f};
        accC[0] = __builtin_amdgcn_mfma_f32_16x16x32_bf16(a1f[0], b.v, zc, 0, 0, 0);
        accC[1] = __builtin_amdgcn_mfma_f32_16x16x32_bf16(a1f[1], b.v, zc, 0, 0, 0);
#pragma unroll
        for (int rt = 0; rt < 2; ++rt)
#pragma unroll
            for (int r = 0; r < 4; ++r)
                sum[rt][r] += __builtin_amdgcn_exp2f(accP[rt][r]);
        accP[0] = accC[0];
        accP[1] = accC[1];
    }
#pragma unroll
    for (int rt = 0; rt < 2; ++rt)
#pragma unroll
        for (int r = 0; r < 4; ++r)
            sum[rt][r] += __builtin_amdgcn_exp2f(accP[rt][r]);

    // ---- epilogue: row-scale by 2^-g_row, wave reduce, per-wave store ----
    float tot = 0.f;
#pragma unroll
    for (int rt = 0; rt < 2; ++rt)
#pragma unroll
        for (int r = 0; r < 4; ++r) {
            const float rs = __builtin_amdgcn_exp2f(-srg[w * 32 + rt * 16 + quad * 4 + r]);
            tot = fmaf(sum[rt][r], rs, tot);
        }
    for (int o = 32; o > 0; o >>= 1) tot += __shfl_down(tot, o, 64);

    if (lane == 0) {
        float wt = (t == 0 || t == 127) ? 1.f : 2.f;
        if (isxx && sq > sa) wt *= 2.f;   // symmetric off-diag strip-pair
        const int idx = isxx ? (2048 + t * 10 + (slot - 16)) : (t * 16 + slot);
        part[idx * 4 + w] = wt * tot;     // per-wave partial, no block reduce
    }
}

__global__ __launch_bounds__(256) void finalize_kernel(const float* __restrict__ part,
                                                       float* __restrict__ out) {
    const int tid = threadIdx.x;
    double vxy = 0.0, vxx = 0.0;
#pragma unroll
    for (int k = 0; k < 32; ++k)  vxy += (double)part[tid + 256 * k];   // [0,8192)
#pragma unroll
    for (int k = 32; k < 52; ++k) vxx += (double)part[tid + 256 * k];   // [8192,13312)
    for (int o = 32; o > 0; o >>= 1) {
        vxx += __shfl_down(vxx, o, 64);
        vxy += __shfl_down(vxy, o, 64);
    }
    __shared__ double red[8];
    const int wid = tid >> 6;
    if ((tid & 63) == 0) { red[wid] = vxx; red[4 + wid] = vxy; }
    __syncthreads();
    if (tid == 0) {
        double sxx = red[0] + red[1] + red[2] + red[3];
        double sxy = red[4] + red[5] + red[6] + red[7];
        // diagonal entries (~1.0 each) included in sxx: subtract 254*512
        double e1 = (sxx - 254.0 * 512.0) / (254.0 * 512.0 * 511.0);
        double e2 = sxy / (254.0 * 512.0 * 512.0);
        out[0] = (float)(e1 - 2.0 * e2);
    }
}

extern "C" void kernel_launch(void* const* d_in, const int* in_sizes, int n_in,
                              void* d_out, int out_size, void* d_ws, size_t ws_size,
                              hipStream_t stream) {
    (void)in_sizes; (void)n_in; (void)out_size; (void)ws_size;
    const float* x = (const float*)d_in[0];
    const float* y = (const float*)d_in[1];
    float* out  = (float*)d_out;
    float* part = (float*)d_ws;   // 13312 floats: [0,8192) xy, [8192,13312) xx

    mmd_kernel<<<dim3(NSLOT, 128), dim3(256), 0, stream>>>(x, y, part);
    finalize_kernel<<<dim3(1), dim3(256), 0, stream>>>(part, out);
}